// Round 2
// baseline (1922.064 us; speedup 1.0000x reference)
//
#include <hip/hip_runtime.h>

// APPNP: h = relu(x@W0+b0)@W1+b1 ; z0=h ; z_{k+1} = 0.9 * (Ahat z_k) + 0.1 * h  (10 iters)
// Ahat = D^-1/2 (A + I) D^-1/2, deg by source(row) incl. self-loop weight 1.
//
// R1: atomics were the bottleneck (k_deg_cnt 282us, ~1000 RMW/cacheline).
// R2: 8-way sharded histograms + sharded scatter cursors (shard = blockIdx&7,
//     identical edge->shard map in both passes so positions stay unique).

#define LDW 68  // LDS pad: 68 mod 32 = 4 -> max 2-way bank aliasing (free)
#define NSH 8

// ---- pass A: sharded histogram (deg by row, cnt by col), 4 edges/thread ----
__global__ __launch_bounds__(256) void k_hist(const int* __restrict__ row, const int* __restrict__ col,
                                              const float* __restrict__ ew,
                                              float* __restrict__ deg_s, int* __restrict__ cnt_s,
                                              int E, int N) {
    int t = blockIdx.x * 256 + threadIdx.x;
    int s = blockIdx.x & (NSH - 1);
    float* dptr = deg_s + (size_t)s * N;
    int*   cptr = cnt_s + (size_t)s * N;
    int e0 = t * 4;
    if (e0 + 4 <= E) {
        int4 r4 = *(const int4*)(row + e0);
        int4 c4 = *(const int4*)(col + e0);
        float4 w4 = *(const float4*)(ew + e0);
        atomicAdd(&dptr[r4.x], w4.x); atomicAdd(&cptr[c4.x], 1);
        atomicAdd(&dptr[r4.y], w4.y); atomicAdd(&cptr[c4.y], 1);
        atomicAdd(&dptr[r4.z], w4.z); atomicAdd(&cptr[c4.z], 1);
        atomicAdd(&dptr[r4.w], w4.w); atomicAdd(&cptr[c4.w], 1);
    } else {
        for (int e = e0; e < E; ++e) {
            atomicAdd(&dptr[row[e]], ew[e]);
            atomicAdd(&cptr[col[e]], 1);
        }
    }
}

// ---- fold shards: dinv = rsqrt(1 + sum deg_s); cnt = sum cnt_s; shoff = per-shard exclusive ----
__global__ __launch_bounds__(256) void k_finish(const float* __restrict__ deg_s, const int* __restrict__ cnt_s,
                                                float* __restrict__ dinv, int* __restrict__ cnt,
                                                int* __restrict__ shoff, int N) {
    int i = blockIdx.x * 256 + threadIdx.x;
    if (i >= N) return;
    float d = 1.0f;  // self-loop weight
#pragma unroll
    for (int s = 0; s < NSH; ++s) d += deg_s[(size_t)s * N + i];
    dinv[i] = d > 0.f ? rsqrtf(d) : 0.f;
    int run = 0;
#pragma unroll
    for (int s = 0; s < NSH; ++s) {
        shoff[(size_t)s * N + i] = run;
        run += cnt_s[(size_t)s * N + i];
    }
    cnt[i] = run;
}

// ---- 3-kernel exclusive scan of cnt[N] -> rowp[N], chunk = 1024 ----
__global__ __launch_bounds__(256) void k_scanA(const int* __restrict__ cnt, int* __restrict__ csum, int N) {
    __shared__ int s[256];
    int t = threadIdx.x, base = blockIdx.x * 1024;
    int p = 0;
#pragma unroll
    for (int j = 0; j < 4; ++j) { int idx = base + t + 256 * j; if (idx < N) p += cnt[idx]; }
    s[t] = p; __syncthreads();
    for (int off = 128; off > 0; off >>= 1) { if (t < off) s[t] += s[t + off]; __syncthreads(); }
    if (t == 0) csum[blockIdx.x] = s[0];
}

__global__ __launch_bounds__(256) void k_scanB(int* __restrict__ csum, int NC) {
    __shared__ int s[256];
    int t = threadIdx.x;
    int v = (t < NC) ? csum[t] : 0;
    s[t] = v; __syncthreads();
    for (int off = 1; off < 256; off <<= 1) {
        int x = (t >= off) ? s[t - off] : 0;
        __syncthreads();
        s[t] += x; __syncthreads();
    }
    if (t < NC) csum[t] = s[t] - v;  // exclusive
}

__global__ __launch_bounds__(256) void k_scanC(const int* __restrict__ cnt, const int* __restrict__ csum,
                                               int* __restrict__ rowp, int N) {
    __shared__ int s[256];
    int t = threadIdx.x, base = blockIdx.x * 1024 + t * 4;
    int c0 = (base + 0 < N) ? cnt[base + 0] : 0;
    int c1 = (base + 1 < N) ? cnt[base + 1] : 0;
    int c2 = (base + 2 < N) ? cnt[base + 2] : 0;
    int c3 = (base + 3 < N) ? cnt[base + 3] : 0;
    int ts = c0 + c1 + c2 + c3;
    s[t] = ts; __syncthreads();
    for (int off = 1; off < 256; off <<= 1) {
        int x = (t >= off) ? s[t - off] : 0;
        __syncthreads();
        s[t] += x; __syncthreads();
    }
    int o = csum[blockIdx.x] + s[t] - ts;
    if (base + 0 < N) rowp[base + 0] = o;
    if (base + 1 < N) rowp[base + 1] = o + c0;
    if (base + 2 < N) rowp[base + 2] = o + c0 + c1;
    if (base + 3 < N) rowp[base + 3] = o + c0 + c1 + c2;
}

// ---- pass C: sharded counting-sort scatter; same edge->shard map as k_hist ----
__global__ __launch_bounds__(256) void k_scatter(const int* __restrict__ row, const int* __restrict__ col,
                                                 const float* __restrict__ ew, const float* __restrict__ dinv,
                                                 const int* __restrict__ rowp, const int* __restrict__ shoff,
                                                 int* __restrict__ cur_s, int2* __restrict__ srcw,
                                                 int E, int N) {
    int t = blockIdx.x * 256 + threadIdx.x;
    int s = blockIdx.x & (NSH - 1);
    const int* shp = shoff + (size_t)s * N;
    int* cur = cur_s + (size_t)s * N;
    int e0 = t * 4;
    if (e0 + 4 <= E) {
        int4 r4 = *(const int4*)(row + e0);
        int4 c4 = *(const int4*)(col + e0);
        float4 w4 = *(const float4*)(ew + e0);
        {
            int pos = rowp[c4.x] + shp[c4.x] + atomicAdd(&cur[c4.x], 1);
            srcw[pos] = make_int2(r4.x, __float_as_int(dinv[r4.x] * w4.x * dinv[c4.x]));
        }
        {
            int pos = rowp[c4.y] + shp[c4.y] + atomicAdd(&cur[c4.y], 1);
            srcw[pos] = make_int2(r4.y, __float_as_int(dinv[r4.y] * w4.y * dinv[c4.y]));
        }
        {
            int pos = rowp[c4.z] + shp[c4.z] + atomicAdd(&cur[c4.z], 1);
            srcw[pos] = make_int2(r4.z, __float_as_int(dinv[r4.z] * w4.z * dinv[c4.z]));
        }
        {
            int pos = rowp[c4.w] + shp[c4.w] + atomicAdd(&cur[c4.w], 1);
            srcw[pos] = make_int2(r4.w, __float_as_int(dinv[r4.w] * w4.w * dinv[c4.w]));
        }
    } else {
        for (int e = e0; e < E; ++e) {
            int c = col[e], r = row[e];
            int pos = rowp[c] + shp[c] + atomicAdd(&cur[c], 1);
            srcw[pos] = make_int2(r, __float_as_int(dinv[r] * ew[e] * dinv[c]));
        }
    }
}

// ---- fused 2-layer MLP: 64 rows x 64 cols per block, 4x4 register tile per thread ----
__global__ __launch_bounds__(256) void k_mlp(const float* __restrict__ x,
                                             const float* __restrict__ W0, const float* __restrict__ b0,
                                             const float* __restrict__ W1, const float* __restrict__ b1,
                                             float* __restrict__ h, int N) {
    __shared__ __align__(16) float xs[64 * LDW];  // xT[k][r] (layer1) / hT[c][r] (layer2)
    __shared__ __align__(16) float ws[64 * LDW];  // W0 chunk / W1  [k][c]
    int tid = threadIdx.x;
    int tc = tid & 15, tr = tid >> 4;            // 16x16 threads, 4x4 outputs each
    int rbase = blockIdx.x * 64;

    float acc[4][4];
#pragma unroll
    for (int i = 0; i < 4; ++i)
#pragma unroll
        for (int j = 0; j < 4; ++j) acc[i][j] = 0.f;

    for (int ck = 0; ck < 8; ++ck) {
        int k0 = ck * 64;
#pragma unroll
        for (int j = 0; j < 4; ++j) {  // stage x chunk transposed
            int l = tid + 256 * j;
            int r = l >> 4, kq = l & 15;
            int gr = rbase + r;
            float4 v = make_float4(0.f, 0.f, 0.f, 0.f);
            if (gr < N) v = *(const float4*)(x + (size_t)gr * 512 + k0 + kq * 4);
            xs[(kq * 4 + 0) * LDW + r] = v.x;
            xs[(kq * 4 + 1) * LDW + r] = v.y;
            xs[(kq * 4 + 2) * LDW + r] = v.z;
            xs[(kq * 4 + 3) * LDW + r] = v.w;
        }
#pragma unroll
        for (int j = 0; j < 4; ++j) {  // stage W0 chunk [k][c]
            int l = tid + 256 * j;
            int kk = l >> 4, cq = l & 15;
            *(float4*)(ws + kk * LDW + cq * 4) = *(const float4*)(W0 + (size_t)(k0 + kk) * 64 + cq * 4);
        }
        __syncthreads();
#pragma unroll 4
        for (int k = 0; k < 64; ++k) {
            float4 a = *(const float4*)(xs + k * LDW + tr * 4);
            float4 w = *(const float4*)(ws + k * LDW + tc * 4);
            acc[0][0] = fmaf(a.x, w.x, acc[0][0]); acc[0][1] = fmaf(a.x, w.y, acc[0][1]);
            acc[0][2] = fmaf(a.x, w.z, acc[0][2]); acc[0][3] = fmaf(a.x, w.w, acc[0][3]);
            acc[1][0] = fmaf(a.y, w.x, acc[1][0]); acc[1][1] = fmaf(a.y, w.y, acc[1][1]);
            acc[1][2] = fmaf(a.y, w.z, acc[1][2]); acc[1][3] = fmaf(a.y, w.w, acc[1][3]);
            acc[2][0] = fmaf(a.z, w.x, acc[2][0]); acc[2][1] = fmaf(a.z, w.y, acc[2][1]);
            acc[2][2] = fmaf(a.z, w.z, acc[2][2]); acc[2][3] = fmaf(a.z, w.w, acc[2][3]);
            acc[3][0] = fmaf(a.w, w.x, acc[3][0]); acc[3][1] = fmaf(a.w, w.y, acc[3][1]);
            acc[3][2] = fmaf(a.w, w.z, acc[3][2]); acc[3][3] = fmaf(a.w, w.w, acc[3][3]);
        }
        __syncthreads();
    }
    // layer-1 epilogue: bias + relu -> hT[c][r] in xs
#pragma unroll
    for (int jj = 0; jj < 4; ++jj) {
        float b = b0[tc * 4 + jj];
        float4 v;
        v.x = fmaxf(acc[0][jj] + b, 0.f);
        v.y = fmaxf(acc[1][jj] + b, 0.f);
        v.z = fmaxf(acc[2][jj] + b, 0.f);
        v.w = fmaxf(acc[3][jj] + b, 0.f);
        *(float4*)(xs + (tc * 4 + jj) * LDW + tr * 4) = v;
    }
#pragma unroll
    for (int j = 0; j < 4; ++j) {  // stage W1 [k][c]
        int l = tid + 256 * j;
        int kk = l >> 4, cq = l & 15;
        *(float4*)(ws + kk * LDW + cq * 4) = *(const float4*)(W1 + (size_t)kk * 64 + cq * 4);
    }
    float acc2[4][4];
#pragma unroll
    for (int i = 0; i < 4; ++i)
#pragma unroll
        for (int j = 0; j < 4; ++j) acc2[i][j] = 0.f;
    __syncthreads();
#pragma unroll 4
    for (int k = 0; k < 64; ++k) {
        float4 a = *(const float4*)(xs + k * LDW + tr * 4);
        float4 w = *(const float4*)(ws + k * LDW + tc * 4);
        acc2[0][0] = fmaf(a.x, w.x, acc2[0][0]); acc2[0][1] = fmaf(a.x, w.y, acc2[0][1]);
        acc2[0][2] = fmaf(a.x, w.z, acc2[0][2]); acc2[0][3] = fmaf(a.x, w.w, acc2[0][3]);
        acc2[1][0] = fmaf(a.y, w.x, acc2[1][0]); acc2[1][1] = fmaf(a.y, w.y, acc2[1][1]);
        acc2[1][2] = fmaf(a.y, w.z, acc2[1][2]); acc2[1][3] = fmaf(a.y, w.w, acc2[1][3]);
        acc2[2][0] = fmaf(a.z, w.x, acc2[2][0]); acc2[2][1] = fmaf(a.z, w.y, acc2[2][1]);
        acc2[2][2] = fmaf(a.z, w.z, acc2[2][2]); acc2[2][3] = fmaf(a.z, w.w, acc2[2][3]);
        acc2[3][0] = fmaf(a.w, w.x, acc2[3][0]); acc2[3][1] = fmaf(a.w, w.y, acc2[3][1]);
        acc2[3][2] = fmaf(a.w, w.z, acc2[3][2]); acc2[3][3] = fmaf(a.w, w.w, acc2[3][3]);
    }
    float bv0 = b1[tc * 4 + 0], bv1 = b1[tc * 4 + 1], bv2 = b1[tc * 4 + 2], bv3 = b1[tc * 4 + 3];
#pragma unroll
    for (int i = 0; i < 4; ++i) {
        int gr = rbase + tr * 4 + i;
        if (gr < N) {
            float4 o = make_float4(acc2[i][0] + bv0, acc2[i][1] + bv1, acc2[i][2] + bv2, acc2[i][3] + bv3);
            *(float4*)(h + (size_t)gr * 64 + tc * 4) = o;
        }
    }
}

// ---- one wave per destination node, lane = feature; pure gather, no atomics ----
__global__ __launch_bounds__(256) void k_prop(const int2* __restrict__ srcw,
                                              const int* __restrict__ rowp, const int* __restrict__ cnt,
                                              const float* __restrict__ dinv,
                                              const float* __restrict__ zin, const float* __restrict__ h,
                                              float* __restrict__ zout, int N) {
    int wid = (blockIdx.x << 2) | (threadIdx.x >> 6);
    int d = __builtin_amdgcn_readfirstlane(wid);  // wave-uniform -> scalar loads for edges
    if (d >= N) return;
    int lane = threadIdx.x & 63;
    size_t dbase = (size_t)d * 64 + lane;
    float di = dinv[d];
    float acc = di * di * zin[dbase];  // analytic self-loop
    int beg = rowp[d], num = cnt[d];
    int e = beg, end = beg + num;
    for (; e + 4 <= end; e += 4) {
        int2 p0 = srcw[e + 0], p1 = srcw[e + 1], p2 = srcw[e + 2], p3 = srcw[e + 3];
        float z0 = zin[(size_t)p0.x * 64 + lane];
        float z1 = zin[(size_t)p1.x * 64 + lane];
        float z2 = zin[(size_t)p2.x * 64 + lane];
        float z3 = zin[(size_t)p3.x * 64 + lane];
        acc = fmaf(__int_as_float(p0.y), z0, acc);
        acc = fmaf(__int_as_float(p1.y), z1, acc);
        acc = fmaf(__int_as_float(p2.y), z2, acc);
        acc = fmaf(__int_as_float(p3.y), z3, acc);
    }
    for (; e < end; ++e) {
        int2 p = srcw[e];
        acc = fmaf(__int_as_float(p.y), zin[(size_t)p.x * 64 + lane], acc);
    }
    zout[dbase] = 0.9f * acc + 0.1f * h[dbase];
}

extern "C" void kernel_launch(void* const* d_in, const int* in_sizes, int n_in,
                              void* d_out, int out_size, void* d_ws, size_t ws_size,
                              hipStream_t stream) {
    const float* x  = (const float*)d_in[0];
    const int*   ei = (const int*)d_in[1];
    const float* ew = (const float*)d_in[2];
    const float* W0 = (const float*)d_in[3];
    const float* b0 = (const float*)d_in[4];
    const float* W1 = (const float*)d_in[5];
    const float* b1 = (const float*)d_in[6];
    int N = in_sizes[0] / 512;
    int E = in_sizes[2];
    const int* row = ei;
    const int* col = ei + E;

    char* p = (char*)d_ws;
    auto alloc = [&](size_t bytes) -> char* {
        char* r = p;
        p += (bytes + 255) & ~(size_t)255;
        return r;
    };
    float* h     = (float*)alloc((size_t)N * 64 * 4);   // 25.6 MB
    float* zA    = (float*)alloc((size_t)N * 64 * 4);   // 25.6 MB
    int2*  srcw  = (int2*)alloc((size_t)E * 8);         // 25.6 MB
    float* dinv  = (float*)alloc((size_t)N * 4);
    int* cnt     = (int*)alloc((size_t)N * 4);
    int* rowp    = (int*)alloc((size_t)N * 4);
    int* csum    = (int*)alloc(256 * 4);
    float* deg_s = (float*)alloc((size_t)NSH * N * 4);  // 3.2 MB
    int* cnt_s   = (int*)alloc((size_t)NSH * N * 4);    // 3.2 MB
    int* shoff   = (int*)alloc((size_t)NSH * N * 4);    // 3.2 MB
    int* cur_s   = (int*)alloc((size_t)NSH * N * 4);    // 3.2 MB

    hipMemsetAsync(deg_s, 0, (size_t)NSH * N * 4, stream);
    hipMemsetAsync(cnt_s, 0, (size_t)NSH * N * 4, stream);
    hipMemsetAsync(cur_s, 0, (size_t)NSH * N * 4, stream);

    int gN = (N + 255) / 256;
    int gE4 = (E + 1023) / 1024;  // 4 edges per thread
    int NC = (N + 1023) / 1024;
    k_hist<<<gE4, 256, 0, stream>>>(row, col, ew, deg_s, cnt_s, E, N);
    k_finish<<<gN, 256, 0, stream>>>(deg_s, cnt_s, dinv, cnt, shoff, N);
    k_scanA<<<NC, 256, 0, stream>>>(cnt, csum, N);
    k_scanB<<<1, 256, 0, stream>>>(csum, NC);
    k_scanC<<<NC, 256, 0, stream>>>(cnt, csum, rowp, N);
    k_scatter<<<gE4, 256, 0, stream>>>(row, col, ew, dinv, rowp, shoff, cur_s, srcw, E, N);
    k_mlp<<<(N + 63) / 64, 256, 0, stream>>>(x, W0, b0, W1, b1, h, N);

    float* bufs[2] = { zA, (float*)d_out };  // iter 10 lands in d_out
    const float* zi = h;
    int gP = (N + 3) / 4;
    for (int it = 0; it < 10; ++it) {
        float* zo = bufs[it & 1];
        k_prop<<<gP, 256, 0, stream>>>(srcw, rowp, cnt, dinv, zi, h, zo, N);
        zi = zo;
    }
}

// Round 3
// 1536.553 us; speedup vs baseline: 1.2509x; 1.2509x over previous
//
#include <hip/hip_runtime.h>

// APPNP: h = relu(x@W0+b0)@W1+b1 ; z0=h ; z_{k+1} = 0.9 * (Ahat z_k) + 0.1 * h  (10 iters)
// Ahat = D^-1/2 (A + I) D^-1/2, deg by source(row) incl. self-loop weight 1.
//
// R2 finding: device-scope atomics are memory-side on MI355X (WRITE_SIZE = 6.4M x 32B),
// fixed ~23G atomics/s regardless of contention spreading. R3: zero global atomics —
// paged LDS histograms + slab fold with deterministic scatter offsets. Also z in bf16
// between iterations (fp32 accumulate, RNE pack; final iter writes fp32).

#define LDW 68     // MLP LDS pad: 68 mod 32 = 4 -> max 2-way bank aliasing (free)
#define PAGE 16128 // dests per page; 16128*4B = 63KB LDS histogram
#define BPP 32     // blocks per page (each scans E/BPP edge chunk)

// ---- deg histogram by row (float, weighted), paged ----
__global__ __launch_bounds__(256) void k_deg(const int* __restrict__ row, const float* __restrict__ ew,
                                             float* __restrict__ slab, int E, int chunk) {
    __shared__ float hf[PAGE];
    int p = blockIdx.x / BPP, b = blockIdx.x - p * BPP;
    int lo = p * PAGE;
    for (int i = threadIdx.x; i < PAGE; i += 256) hf[i] = 0.f;
    __syncthreads();
    int e0 = b * chunk, e1 = min(e0 + chunk, E);
    int evec = e0 + ((e1 - e0) & ~3);
    for (int e = e0 + (int)threadIdx.x * 4; e + 4 <= evec; e += 1024) {
        int4 r4 = *(const int4*)(row + e);
        float4 w4 = *(const float4*)(ew + e);
        unsigned a = (unsigned)(r4.x - lo), bq = (unsigned)(r4.y - lo);
        unsigned c = (unsigned)(r4.z - lo), dq = (unsigned)(r4.w - lo);
        if (a < PAGE) atomicAdd(&hf[a], w4.x);
        if (bq < PAGE) atomicAdd(&hf[bq], w4.y);
        if (c < PAGE) atomicAdd(&hf[c], w4.z);
        if (dq < PAGE) atomicAdd(&hf[dq], w4.w);
    }
    for (int e = evec + (int)threadIdx.x; e < e1; e += 256) {
        unsigned a = (unsigned)(row[e] - lo);
        if (a < PAGE) atomicAdd(&hf[a], ew[e]);
    }
    __syncthreads();
    float* out = slab + (size_t)blockIdx.x * PAGE;
    for (int i = threadIdx.x; i < PAGE; i += 256) out[i] = hf[i];
}

__global__ __launch_bounds__(256) void k_fold_deg(const float* __restrict__ slab, float* __restrict__ dinv, int N) {
    int i = blockIdx.x * 256 + threadIdx.x;
    if (i >= N) return;
    int p = i / PAGE, ld = i - p * PAGE;
    const float* base = slab + (size_t)(p * BPP) * PAGE + ld;
    float d = 1.0f;  // self-loop weight
#pragma unroll
    for (int b = 0; b < BPP; ++b) d += base[(size_t)b * PAGE];
    dinv[i] = d > 0.f ? rsqrtf(d) : 0.f;
}

// ---- cnt histogram by col (int), paged ----
__global__ __launch_bounds__(256) void k_cnt(const int* __restrict__ col, int* __restrict__ slab,
                                             int E, int chunk) {
    __shared__ int hi[PAGE];
    int p = blockIdx.x / BPP, b = blockIdx.x - p * BPP;
    int lo = p * PAGE;
    for (int i = threadIdx.x; i < PAGE; i += 256) hi[i] = 0;
    __syncthreads();
    int e0 = b * chunk, e1 = min(e0 + chunk, E);
    int evec = e0 + ((e1 - e0) & ~3);
    for (int e = e0 + (int)threadIdx.x * 4; e + 4 <= evec; e += 1024) {
        int4 c4 = *(const int4*)(col + e);
        unsigned a = (unsigned)(c4.x - lo), bq = (unsigned)(c4.y - lo);
        unsigned c = (unsigned)(c4.z - lo), dq = (unsigned)(c4.w - lo);
        if (a < PAGE) atomicAdd(&hi[a], 1);
        if (bq < PAGE) atomicAdd(&hi[bq], 1);
        if (c < PAGE) atomicAdd(&hi[c], 1);
        if (dq < PAGE) atomicAdd(&hi[dq], 1);
    }
    for (int e = evec + (int)threadIdx.x; e < e1; e += 256) {
        unsigned a = (unsigned)(col[e] - lo);
        if (a < PAGE) atomicAdd(&hi[a], 1);
    }
    __syncthreads();
    int* out = slab + (size_t)blockIdx.x * PAGE;
    for (int i = threadIdx.x; i < PAGE; i += 256) out[i] = hi[i];
}

// fold cnt: total per dest + per-block exclusive offsets written back in place
__global__ __launch_bounds__(256) void k_fold_cnt(int* __restrict__ slab, int* __restrict__ cnt, int N) {
    int i = blockIdx.x * 256 + threadIdx.x;
    if (i >= N) return;
    int p = i / PAGE, ld = i - p * PAGE;
    int* base = slab + (size_t)(p * BPP) * PAGE + ld;
    int run = 0;
#pragma unroll
    for (int b = 0; b < BPP; ++b) {
        size_t off = (size_t)b * PAGE;
        int v = base[off];
        base[off] = run;
        run += v;
    }
    cnt[i] = run;
}

// ---- 3-kernel exclusive scan of cnt[N] -> rowp[N], chunk = 1024 ----
__global__ __launch_bounds__(256) void k_scanA(const int* __restrict__ cnt, int* __restrict__ csum, int N) {
    __shared__ int s[256];
    int t = threadIdx.x, base = blockIdx.x * 1024;
    int p = 0;
#pragma unroll
    for (int j = 0; j < 4; ++j) { int idx = base + t + 256 * j; if (idx < N) p += cnt[idx]; }
    s[t] = p; __syncthreads();
    for (int off = 128; off > 0; off >>= 1) { if (t < off) s[t] += s[t + off]; __syncthreads(); }
    if (t == 0) csum[blockIdx.x] = s[0];
}

__global__ __launch_bounds__(256) void k_scanB(int* __restrict__ csum, int NC) {
    __shared__ int s[256];
    int t = threadIdx.x;
    int v = (t < NC) ? csum[t] : 0;
    s[t] = v; __syncthreads();
    for (int off = 1; off < 256; off <<= 1) {
        int x = (t >= off) ? s[t - off] : 0;
        __syncthreads();
        s[t] += x; __syncthreads();
    }
    if (t < NC) csum[t] = s[t] - v;  // exclusive
}

__global__ __launch_bounds__(256) void k_scanC(const int* __restrict__ cnt, const int* __restrict__ csum,
                                               int* __restrict__ rowp, int N) {
    __shared__ int s[256];
    int t = threadIdx.x, base = blockIdx.x * 1024 + t * 4;
    int c0 = (base + 0 < N) ? cnt[base + 0] : 0;
    int c1 = (base + 1 < N) ? cnt[base + 1] : 0;
    int c2 = (base + 2 < N) ? cnt[base + 2] : 0;
    int c3 = (base + 3 < N) ? cnt[base + 3] : 0;
    int ts = c0 + c1 + c2 + c3;
    s[t] = ts; __syncthreads();
    for (int off = 1; off < 256; off <<= 1) {
        int x = (t >= off) ? s[t - off] : 0;
        __syncthreads();
        s[t] += x; __syncthreads();
    }
    int o = csum[blockIdx.x] + s[t] - ts;
    if (base + 0 < N) rowp[base + 0] = o;
    if (base + 1 < N) rowp[base + 1] = o + c0;
    if (base + 2 < N) rowp[base + 2] = o + c0 + c1;
    if (base + 3 < N) rowp[base + 3] = o + c0 + c1 + c2;
}

// ---- scatter: deterministic positions, LDS cursors only (same chunk map as k_cnt) ----
__global__ __launch_bounds__(256) void k_scat(const int* __restrict__ row, const int* __restrict__ col,
                                              const float* __restrict__ ew, const float* __restrict__ dinv,
                                              const int* __restrict__ rowp, const int* __restrict__ slab,
                                              int2* __restrict__ srcw, int E, int chunk) {
    __shared__ int cur[PAGE];
    int p = blockIdx.x / BPP, b = blockIdx.x - p * BPP;
    int lo = p * PAGE;
    for (int i = threadIdx.x; i < PAGE; i += 256) cur[i] = 0;
    __syncthreads();
    const int* soff = slab + (size_t)blockIdx.x * PAGE;
    int e0 = b * chunk, e1 = min(e0 + chunk, E);
    int evec = e0 + ((e1 - e0) & ~3);
    for (int e = e0 + (int)threadIdx.x * 4; e + 4 <= evec; e += 1024) {
        int4 c4 = *(const int4*)(col + e);
        unsigned a = (unsigned)(c4.x - lo), bq = (unsigned)(c4.y - lo);
        unsigned cc = (unsigned)(c4.z - lo), dq = (unsigned)(c4.w - lo);
        if ((a < PAGE) | (bq < PAGE) | (cc < PAGE) | (dq < PAGE)) {
            int4 r4 = *(const int4*)(row + e);
            float4 w4 = *(const float4*)(ew + e);
            if (a < PAGE) {
                int pos = rowp[c4.x] + soff[a] + atomicAdd(&cur[a], 1);
                srcw[pos] = make_int2(r4.x, __float_as_int(dinv[r4.x] * w4.x * dinv[c4.x]));
            }
            if (bq < PAGE) {
                int pos = rowp[c4.y] + soff[bq] + atomicAdd(&cur[bq], 1);
                srcw[pos] = make_int2(r4.y, __float_as_int(dinv[r4.y] * w4.y * dinv[c4.y]));
            }
            if (cc < PAGE) {
                int pos = rowp[c4.z] + soff[cc] + atomicAdd(&cur[cc], 1);
                srcw[pos] = make_int2(r4.z, __float_as_int(dinv[r4.z] * w4.z * dinv[c4.z]));
            }
            if (dq < PAGE) {
                int pos = rowp[c4.w] + soff[dq] + atomicAdd(&cur[dq], 1);
                srcw[pos] = make_int2(r4.w, __float_as_int(dinv[r4.w] * w4.w * dinv[c4.w]));
            }
        }
    }
    for (int e = evec + (int)threadIdx.x; e < e1; e += 256) {
        int c = col[e];
        unsigned a = (unsigned)(c - lo);
        if (a < PAGE) {
            int r = row[e];
            int pos = rowp[c] + soff[a] + atomicAdd(&cur[a], 1);
            srcw[pos] = make_int2(r, __float_as_int(dinv[r] * ew[e] * dinv[c]));
        }
    }
}

// ---- fused 2-layer MLP: 64 rows x 64 cols per block, 4x4 register tile per thread ----
__global__ __launch_bounds__(256) void k_mlp(const float* __restrict__ x,
                                             const float* __restrict__ W0, const float* __restrict__ b0,
                                             const float* __restrict__ W1, const float* __restrict__ b1,
                                             float* __restrict__ h, int N) {
    __shared__ __align__(16) float xs[64 * LDW];
    __shared__ __align__(16) float ws[64 * LDW];
    int tid = threadIdx.x;
    int tc = tid & 15, tr = tid >> 4;
    int rbase = blockIdx.x * 64;

    float acc[4][4];
#pragma unroll
    for (int i = 0; i < 4; ++i)
#pragma unroll
        for (int j = 0; j < 4; ++j) acc[i][j] = 0.f;

    for (int ck = 0; ck < 8; ++ck) {
        int k0 = ck * 64;
#pragma unroll
        for (int j = 0; j < 4; ++j) {
            int l = tid + 256 * j;
            int r = l >> 4, kq = l & 15;
            int gr = rbase + r;
            float4 v = make_float4(0.f, 0.f, 0.f, 0.f);
            if (gr < N) v = *(const float4*)(x + (size_t)gr * 512 + k0 + kq * 4);
            xs[(kq * 4 + 0) * LDW + r] = v.x;
            xs[(kq * 4 + 1) * LDW + r] = v.y;
            xs[(kq * 4 + 2) * LDW + r] = v.z;
            xs[(kq * 4 + 3) * LDW + r] = v.w;
        }
#pragma unroll
        for (int j = 0; j < 4; ++j) {
            int l = tid + 256 * j;
            int kk = l >> 4, cq = l & 15;
            *(float4*)(ws + kk * LDW + cq * 4) = *(const float4*)(W0 + (size_t)(k0 + kk) * 64 + cq * 4);
        }
        __syncthreads();
#pragma unroll 4
        for (int k = 0; k < 64; ++k) {
            float4 a = *(const float4*)(xs + k * LDW + tr * 4);
            float4 w = *(const float4*)(ws + k * LDW + tc * 4);
            acc[0][0] = fmaf(a.x, w.x, acc[0][0]); acc[0][1] = fmaf(a.x, w.y, acc[0][1]);
            acc[0][2] = fmaf(a.x, w.z, acc[0][2]); acc[0][3] = fmaf(a.x, w.w, acc[0][3]);
            acc[1][0] = fmaf(a.y, w.x, acc[1][0]); acc[1][1] = fmaf(a.y, w.y, acc[1][1]);
            acc[1][2] = fmaf(a.y, w.z, acc[1][2]); acc[1][3] = fmaf(a.y, w.w, acc[1][3]);
            acc[2][0] = fmaf(a.z, w.x, acc[2][0]); acc[2][1] = fmaf(a.z, w.y, acc[2][1]);
            acc[2][2] = fmaf(a.z, w.z, acc[2][2]); acc[2][3] = fmaf(a.z, w.w, acc[2][3]);
            acc[3][0] = fmaf(a.w, w.x, acc[3][0]); acc[3][1] = fmaf(a.w, w.y, acc[3][1]);
            acc[3][2] = fmaf(a.w, w.z, acc[3][2]); acc[3][3] = fmaf(a.w, w.w, acc[3][3]);
        }
        __syncthreads();
    }
#pragma unroll
    for (int jj = 0; jj < 4; ++jj) {
        float b = b0[tc * 4 + jj];
        float4 v;
        v.x = fmaxf(acc[0][jj] + b, 0.f);
        v.y = fmaxf(acc[1][jj] + b, 0.f);
        v.z = fmaxf(acc[2][jj] + b, 0.f);
        v.w = fmaxf(acc[3][jj] + b, 0.f);
        *(float4*)(xs + (tc * 4 + jj) * LDW + tr * 4) = v;
    }
#pragma unroll
    for (int j = 0; j < 4; ++j) {
        int l = tid + 256 * j;
        int kk = l >> 4, cq = l & 15;
        *(float4*)(ws + kk * LDW + cq * 4) = *(const float4*)(W1 + (size_t)kk * 64 + cq * 4);
    }
    float acc2[4][4];
#pragma unroll
    for (int i = 0; i < 4; ++i)
#pragma unroll
        for (int j = 0; j < 4; ++j) acc2[i][j] = 0.f;
    __syncthreads();
#pragma unroll 4
    for (int k = 0; k < 64; ++k) {
        float4 a = *(const float4*)(xs + k * LDW + tr * 4);
        float4 w = *(const float4*)(ws + k * LDW + tc * 4);
        acc2[0][0] = fmaf(a.x, w.x, acc2[0][0]); acc2[0][1] = fmaf(a.x, w.y, acc2[0][1]);
        acc2[0][2] = fmaf(a.x, w.z, acc2[0][2]); acc2[0][3] = fmaf(a.x, w.w, acc2[0][3]);
        acc2[1][0] = fmaf(a.y, w.x, acc2[1][0]); acc2[1][1] = fmaf(a.y, w.y, acc2[1][1]);
        acc2[1][2] = fmaf(a.y, w.z, acc2[1][2]); acc2[1][3] = fmaf(a.y, w.w, acc2[1][3]);
        acc2[2][0] = fmaf(a.z, w.x, acc2[2][0]); acc2[2][1] = fmaf(a.z, w.y, acc2[2][1]);
        acc2[2][2] = fmaf(a.z, w.z, acc2[2][2]); acc2[2][3] = fmaf(a.z, w.w, acc2[2][3]);
        acc2[3][0] = fmaf(a.w, w.x, acc2[3][0]); acc2[3][1] = fmaf(a.w, w.y, acc2[3][1]);
        acc2[3][2] = fmaf(a.w, w.z, acc2[3][2]); acc2[3][3] = fmaf(a.w, w.w, acc2[3][3]);
    }
    float bv0 = b1[tc * 4 + 0], bv1 = b1[tc * 4 + 1], bv2 = b1[tc * 4 + 2], bv3 = b1[tc * 4 + 3];
#pragma unroll
    for (int i = 0; i < 4; ++i) {
        int gr = rbase + tr * 4 + i;
        if (gr < N) {
            float4 o = make_float4(acc2[i][0] + bv0, acc2[i][1] + bv1, acc2[i][2] + bv2, acc2[i][3] + bv3);
            *(float4*)(h + (size_t)gr * 64 + tc * 4) = o;
        }
    }
}

// ---- bf16 helpers ----
__device__ __forceinline__ float bf_lo(unsigned z) { return __uint_as_float(z << 16); }
__device__ __forceinline__ float bf_hi(unsigned z) { return __uint_as_float(z & 0xffff0000u); }
__device__ __forceinline__ unsigned bf_rne(float x) {
    unsigned u = __float_as_uint(x);
    return (u + 0x7fffu + ((u >> 16) & 1u)) >> 16;
}
__device__ __forceinline__ unsigned bf_pack(float x, float y) { return bf_rne(x) | (bf_rne(y) << 16); }

__global__ __launch_bounds__(256) void k_h2b(const float* __restrict__ h, unsigned* __restrict__ zb, int n2) {
    int i = blockIdx.x * 256 + threadIdx.x;
    if (i < n2) {
        float2 v = ((const float2*)h)[i];
        zb[i] = bf_pack(v.x, v.y);
    }
}

// ---- propagation: wave per dest, 2 edges x 32 lanes, bf16 z gather (128B/edge) ----
__global__ __launch_bounds__(256) void k_prop(const int2* __restrict__ srcw,
                                              const int* __restrict__ rowp, const int* __restrict__ cnt,
                                              const float* __restrict__ dinv,
                                              const unsigned* __restrict__ zin, const float* __restrict__ h,
                                              unsigned* __restrict__ zout_b, float* __restrict__ zout_f, int N) {
    int wid = (blockIdx.x << 2) | (threadIdx.x >> 6);
    int d = __builtin_amdgcn_readfirstlane(wid);  // wave-uniform -> scalar loads for per-dest data
    if (d >= N) return;
    int lane = threadIdx.x & 63;
    int half = lane >> 5, fi = lane & 31;  // lane handles features (2fi, 2fi+1) of edge parity `half`
    int beg = rowp[d], end = beg + cnt[d];
    float ax = 0.f, ay = 0.f;
    int e = beg + half;
    for (; e + 6 < end; e += 8) {
        int2 p0 = srcw[e], p1 = srcw[e + 2], p2 = srcw[e + 4], p3 = srcw[e + 6];
        unsigned z0 = zin[(size_t)p0.x * 32 + fi];
        unsigned z1 = zin[(size_t)p1.x * 32 + fi];
        unsigned z2 = zin[(size_t)p2.x * 32 + fi];
        unsigned z3 = zin[(size_t)p3.x * 32 + fi];
        float w0 = __int_as_float(p0.y), w1 = __int_as_float(p1.y);
        float w2 = __int_as_float(p2.y), w3 = __int_as_float(p3.y);
        ax = fmaf(w0, bf_lo(z0), ax); ay = fmaf(w0, bf_hi(z0), ay);
        ax = fmaf(w1, bf_lo(z1), ax); ay = fmaf(w1, bf_hi(z1), ay);
        ax = fmaf(w2, bf_lo(z2), ax); ay = fmaf(w2, bf_hi(z2), ay);
        ax = fmaf(w3, bf_lo(z3), ax); ay = fmaf(w3, bf_hi(z3), ay);
    }
    for (; e < end; e += 2) {
        int2 p = srcw[e];
        unsigned z = zin[(size_t)p.x * 32 + fi];
        float w = __int_as_float(p.y);
        ax = fmaf(w, bf_lo(z), ax); ay = fmaf(w, bf_hi(z), ay);
    }
    ax += __shfl_xor(ax, 32);
    ay += __shfl_xor(ay, 32);
    if (half == 0) {
        float di = dinv[d];
        unsigned zs = zin[(size_t)d * 32 + fi];  // analytic self-loop
        float s2 = di * di;
        float ox = 0.9f * (ax + s2 * bf_lo(zs));
        float oy = 0.9f * (ay + s2 * bf_hi(zs));
        float2 hv = ((const float2*)h)[(size_t)d * 32 + fi];
        ox = fmaf(0.1f, hv.x, ox);
        oy = fmaf(0.1f, hv.y, oy);
        if (zout_f) ((float2*)zout_f)[(size_t)d * 32 + fi] = make_float2(ox, oy);
        else zout_b[(size_t)d * 32 + fi] = bf_pack(ox, oy);
    }
}

extern "C" void kernel_launch(void* const* d_in, const int* in_sizes, int n_in,
                              void* d_out, int out_size, void* d_ws, size_t ws_size,
                              hipStream_t stream) {
    const float* x  = (const float*)d_in[0];
    const int*   ei = (const int*)d_in[1];
    const float* ew = (const float*)d_in[2];
    const float* W0 = (const float*)d_in[3];
    const float* b0 = (const float*)d_in[4];
    const float* W1 = (const float*)d_in[5];
    const float* b1 = (const float*)d_in[6];
    int N = in_sizes[0] / 512;
    int E = in_sizes[2];
    const int* row = ei;
    const int* col = ei + E;

    char* p = (char*)d_ws;
    auto alloc = [&](size_t bytes) -> char* {
        char* r = p;
        p += (bytes + 255) & ~(size_t)255;
        return r;
    };
    int NPg = (N + PAGE - 1) / PAGE;                        // 7 pages for N=100K
    float* h     = (float*)alloc((size_t)N * 64 * 4);       // 25.6 MB
    unsigned* zb0 = (unsigned*)alloc((size_t)N * 32 * 4);   // 12.8 MB (bf16x2)
    unsigned* zb1 = (unsigned*)alloc((size_t)N * 32 * 4);   // 12.8 MB
    int2*  srcw  = (int2*)alloc((size_t)E * 8);             // 25.6 MB
    float* slabf = (float*)alloc((size_t)NPg * BPP * PAGE * 4);  // 14.4 MB (reused int)
    float* dinv  = (float*)alloc((size_t)N * 4);
    int* cnt     = (int*)alloc((size_t)N * 4);
    int* rowp    = (int*)alloc((size_t)N * 4);
    int* csum    = (int*)alloc(256 * 4);
    int* slabi   = (int*)slabf;  // sequential reuse: deg fold completes before k_cnt writes

    int gN = (N + 255) / 256;
    int NC = (N + 1023) / 1024;
    int chunk = (((E + BPP - 1) / BPP) + 3) & ~3;
    int gridPg = NPg * BPP;

    k_deg<<<gridPg, 256, 0, stream>>>(row, ew, slabf, E, chunk);
    k_fold_deg<<<gN, 256, 0, stream>>>(slabf, dinv, N);
    k_cnt<<<gridPg, 256, 0, stream>>>(col, slabi, E, chunk);
    k_fold_cnt<<<gN, 256, 0, stream>>>(slabi, cnt, N);
    k_scanA<<<NC, 256, 0, stream>>>(cnt, csum, N);
    k_scanB<<<1, 256, 0, stream>>>(csum, NC);
    k_scanC<<<NC, 256, 0, stream>>>(cnt, csum, rowp, N);
    k_scat<<<gridPg, 256, 0, stream>>>(row, col, ew, dinv, rowp, slabi, srcw, E, chunk);
    k_mlp<<<(N + 63) / 64, 256, 0, stream>>>(x, W0, b0, W1, b1, h, N);
    k_h2b<<<(N * 32 + 255) / 256, 256, 0, stream>>>(h, zb0, N * 32);

    unsigned* zbufs[2] = { zb1, zb0 };  // iter it writes zbufs[it&1] (bf16) except final
    const unsigned* zi = zb0;
    int gP = (N + 3) / 4;
    for (int it = 0; it < 10; ++it) {
        if (it < 9) {
            unsigned* zo = zbufs[it & 1];
            k_prop<<<gP, 256, 0, stream>>>(srcw, rowp, cnt, dinv, zi, h, zo, nullptr, N);
            zi = zo;
        } else {
            k_prop<<<gP, 256, 0, stream>>>(srcw, rowp, cnt, dinv, zi, h, nullptr, (float*)d_out, N);
        }
    }
}

// Round 4
// 1511.109 us; speedup vs baseline: 1.2720x; 1.0168x over previous
//
#include <hip/hip_runtime.h>

// APPNP: h = relu(x@W0+b0)@W1+b1 ; z0=h ; z_{k+1} = 0.9 * (Ahat z_k) + 0.1 * h  (10 iters)
// Ahat = D^-1/2 (A + I) D^-1/2, deg by source(row) incl. self-loop weight 1.
//
// R2: device-scope atomics are memory-side (~23G/s fixed) -> eliminated (paged LDS hist).
// R3 finding: paged kernels were grid-starved (224 blocks, Occupancy 9.4%, VALU 5%).
// R4: BPP 32->64 (448 blocks, 2 blocks/CU LDS limit fully used); k_prop unroll 8
//     (8 outstanding gathers/lane); zb buffers overlaid on dead slab region.

#define LDW 68     // MLP LDS pad: 68 mod 32 = 4 -> max 2-way bank aliasing (free)
#define PAGE 16128 // dests per page; 16128*4B = 63KB LDS histogram -> 2 blocks/CU
#define BPP 64     // blocks per page (each scans E/BPP edge chunk)

// ---- deg histogram by row (float, weighted), paged ----
__global__ __launch_bounds__(256) void k_deg(const int* __restrict__ row, const float* __restrict__ ew,
                                             float* __restrict__ slab, int E, int chunk) {
    __shared__ float hf[PAGE];
    int p = blockIdx.x / BPP, b = blockIdx.x - p * BPP;
    int lo = p * PAGE;
    for (int i = threadIdx.x; i < PAGE; i += 256) hf[i] = 0.f;
    __syncthreads();
    int e0 = b * chunk, e1 = min(e0 + chunk, E);
    int evec = e0 + ((e1 - e0) & ~3);
    for (int e = e0 + (int)threadIdx.x * 4; e + 4 <= evec; e += 1024) {
        int4 r4 = *(const int4*)(row + e);
        float4 w4 = *(const float4*)(ew + e);
        unsigned a = (unsigned)(r4.x - lo), bq = (unsigned)(r4.y - lo);
        unsigned c = (unsigned)(r4.z - lo), dq = (unsigned)(r4.w - lo);
        if (a < PAGE) atomicAdd(&hf[a], w4.x);
        if (bq < PAGE) atomicAdd(&hf[bq], w4.y);
        if (c < PAGE) atomicAdd(&hf[c], w4.z);
        if (dq < PAGE) atomicAdd(&hf[dq], w4.w);
    }
    for (int e = evec + (int)threadIdx.x; e < e1; e += 256) {
        unsigned a = (unsigned)(row[e] - lo);
        if (a < PAGE) atomicAdd(&hf[a], ew[e]);
    }
    __syncthreads();
    float* out = slab + (size_t)blockIdx.x * PAGE;
    for (int i = threadIdx.x; i < PAGE; i += 256) out[i] = hf[i];
}

__global__ __launch_bounds__(256) void k_fold_deg(const float* __restrict__ slab, float* __restrict__ dinv, int N) {
    int i = blockIdx.x * 256 + threadIdx.x;
    if (i >= N) return;
    int p = i / PAGE, ld = i - p * PAGE;
    const float* base = slab + (size_t)(p * BPP) * PAGE + ld;
    float d = 1.0f;  // self-loop weight
#pragma unroll
    for (int b = 0; b < BPP; ++b) d += base[(size_t)b * PAGE];
    dinv[i] = d > 0.f ? rsqrtf(d) : 0.f;
}

// ---- cnt histogram by col (int), paged ----
__global__ __launch_bounds__(256) void k_cnt(const int* __restrict__ col, int* __restrict__ slab,
                                             int E, int chunk) {
    __shared__ int hi[PAGE];
    int p = blockIdx.x / BPP, b = blockIdx.x - p * BPP;
    int lo = p * PAGE;
    for (int i = threadIdx.x; i < PAGE; i += 256) hi[i] = 0;
    __syncthreads();
    int e0 = b * chunk, e1 = min(e0 + chunk, E);
    int evec = e0 + ((e1 - e0) & ~3);
    for (int e = e0 + (int)threadIdx.x * 4; e + 4 <= evec; e += 1024) {
        int4 c4 = *(const int4*)(col + e);
        unsigned a = (unsigned)(c4.x - lo), bq = (unsigned)(c4.y - lo);
        unsigned c = (unsigned)(c4.z - lo), dq = (unsigned)(c4.w - lo);
        if (a < PAGE) atomicAdd(&hi[a], 1);
        if (bq < PAGE) atomicAdd(&hi[bq], 1);
        if (c < PAGE) atomicAdd(&hi[c], 1);
        if (dq < PAGE) atomicAdd(&hi[dq], 1);
    }
    for (int e = evec + (int)threadIdx.x; e < e1; e += 256) {
        unsigned a = (unsigned)(col[e] - lo);
        if (a < PAGE) atomicAdd(&hi[a], 1);
    }
    __syncthreads();
    int* out = slab + (size_t)blockIdx.x * PAGE;
    for (int i = threadIdx.x; i < PAGE; i += 256) out[i] = hi[i];
}

// fold cnt: total per dest + per-block exclusive offsets written back in place
__global__ __launch_bounds__(256) void k_fold_cnt(int* __restrict__ slab, int* __restrict__ cnt, int N) {
    int i = blockIdx.x * 256 + threadIdx.x;
    if (i >= N) return;
    int p = i / PAGE, ld = i - p * PAGE;
    int* base = slab + (size_t)(p * BPP) * PAGE + ld;
    int run = 0;
#pragma unroll
    for (int b = 0; b < BPP; ++b) {
        size_t off = (size_t)b * PAGE;
        int v = base[off];
        base[off] = run;
        run += v;
    }
    cnt[i] = run;
}

// ---- 3-kernel exclusive scan of cnt[N] -> rowp[N], chunk = 1024 ----
__global__ __launch_bounds__(256) void k_scanA(const int* __restrict__ cnt, int* __restrict__ csum, int N) {
    __shared__ int s[256];
    int t = threadIdx.x, base = blockIdx.x * 1024;
    int p = 0;
#pragma unroll
    for (int j = 0; j < 4; ++j) { int idx = base + t + 256 * j; if (idx < N) p += cnt[idx]; }
    s[t] = p; __syncthreads();
    for (int off = 128; off > 0; off >>= 1) { if (t < off) s[t] += s[t + off]; __syncthreads(); }
    if (t == 0) csum[blockIdx.x] = s[0];
}

__global__ __launch_bounds__(256) void k_scanB(int* __restrict__ csum, int NC) {
    __shared__ int s[256];
    int t = threadIdx.x;
    int v = (t < NC) ? csum[t] : 0;
    s[t] = v; __syncthreads();
    for (int off = 1; off < 256; off <<= 1) {
        int x = (t >= off) ? s[t - off] : 0;
        __syncthreads();
        s[t] += x; __syncthreads();
    }
    if (t < NC) csum[t] = s[t] - v;  // exclusive
}

__global__ __launch_bounds__(256) void k_scanC(const int* __restrict__ cnt, const int* __restrict__ csum,
                                               int* __restrict__ rowp, int N) {
    __shared__ int s[256];
    int t = threadIdx.x, base = blockIdx.x * 1024 + t * 4;
    int c0 = (base + 0 < N) ? cnt[base + 0] : 0;
    int c1 = (base + 1 < N) ? cnt[base + 1] : 0;
    int c2 = (base + 2 < N) ? cnt[base + 2] : 0;
    int c3 = (base + 3 < N) ? cnt[base + 3] : 0;
    int ts = c0 + c1 + c2 + c3;
    s[t] = ts; __syncthreads();
    for (int off = 1; off < 256; off <<= 1) {
        int x = (t >= off) ? s[t - off] : 0;
        __syncthreads();
        s[t] += x; __syncthreads();
    }
    int o = csum[blockIdx.x] + s[t] - ts;
    if (base + 0 < N) rowp[base + 0] = o;
    if (base + 1 < N) rowp[base + 1] = o + c0;
    if (base + 2 < N) rowp[base + 2] = o + c0 + c1;
    if (base + 3 < N) rowp[base + 3] = o + c0 + c1 + c2;
}

// ---- scatter: deterministic positions, LDS cursors only (same chunk map as k_cnt) ----
__global__ __launch_bounds__(256) void k_scat(const int* __restrict__ row, const int* __restrict__ col,
                                              const float* __restrict__ ew, const float* __restrict__ dinv,
                                              const int* __restrict__ rowp, const int* __restrict__ slab,
                                              int2* __restrict__ srcw, int E, int chunk) {
    __shared__ int cur[PAGE];
    int p = blockIdx.x / BPP, b = blockIdx.x - p * BPP;
    int lo = p * PAGE;
    for (int i = threadIdx.x; i < PAGE; i += 256) cur[i] = 0;
    __syncthreads();
    const int* soff = slab + (size_t)blockIdx.x * PAGE;
    int e0 = b * chunk, e1 = min(e0 + chunk, E);
    int evec = e0 + ((e1 - e0) & ~3);
    for (int e = e0 + (int)threadIdx.x * 4; e + 4 <= evec; e += 1024) {
        int4 c4 = *(const int4*)(col + e);
        unsigned a = (unsigned)(c4.x - lo), bq = (unsigned)(c4.y - lo);
        unsigned cc = (unsigned)(c4.z - lo), dq = (unsigned)(c4.w - lo);
        if ((a < PAGE) | (bq < PAGE) | (cc < PAGE) | (dq < PAGE)) {
            int4 r4 = *(const int4*)(row + e);
            float4 w4 = *(const float4*)(ew + e);
            if (a < PAGE) {
                int pos = rowp[c4.x] + soff[a] + atomicAdd(&cur[a], 1);
                srcw[pos] = make_int2(r4.x, __float_as_int(dinv[r4.x] * w4.x * dinv[c4.x]));
            }
            if (bq < PAGE) {
                int pos = rowp[c4.y] + soff[bq] + atomicAdd(&cur[bq], 1);
                srcw[pos] = make_int2(r4.y, __float_as_int(dinv[r4.y] * w4.y * dinv[c4.y]));
            }
            if (cc < PAGE) {
                int pos = rowp[c4.z] + soff[cc] + atomicAdd(&cur[cc], 1);
                srcw[pos] = make_int2(r4.z, __float_as_int(dinv[r4.z] * w4.z * dinv[c4.z]));
            }
            if (dq < PAGE) {
                int pos = rowp[c4.w] + soff[dq] + atomicAdd(&cur[dq], 1);
                srcw[pos] = make_int2(r4.w, __float_as_int(dinv[r4.w] * w4.w * dinv[c4.w]));
            }
        }
    }
    for (int e = evec + (int)threadIdx.x; e < e1; e += 256) {
        int c = col[e];
        unsigned a = (unsigned)(c - lo);
        if (a < PAGE) {
            int r = row[e];
            int pos = rowp[c] + soff[a] + atomicAdd(&cur[a], 1);
            srcw[pos] = make_int2(r, __float_as_int(dinv[r] * ew[e] * dinv[c]));
        }
    }
}

// ---- fused 2-layer MLP: 64 rows x 64 cols per block, 4x4 register tile per thread ----
__global__ __launch_bounds__(256) void k_mlp(const float* __restrict__ x,
                                             const float* __restrict__ W0, const float* __restrict__ b0,
                                             const float* __restrict__ W1, const float* __restrict__ b1,
                                             float* __restrict__ h, int N) {
    __shared__ __align__(16) float xs[64 * LDW];
    __shared__ __align__(16) float ws[64 * LDW];
    int tid = threadIdx.x;
    int tc = tid & 15, tr = tid >> 4;
    int rbase = blockIdx.x * 64;

    float acc[4][4];
#pragma unroll
    for (int i = 0; i < 4; ++i)
#pragma unroll
        for (int j = 0; j < 4; ++j) acc[i][j] = 0.f;

    for (int ck = 0; ck < 8; ++ck) {
        int k0 = ck * 64;
#pragma unroll
        for (int j = 0; j < 4; ++j) {
            int l = tid + 256 * j;
            int r = l >> 4, kq = l & 15;
            int gr = rbase + r;
            float4 v = make_float4(0.f, 0.f, 0.f, 0.f);
            if (gr < N) v = *(const float4*)(x + (size_t)gr * 512 + k0 + kq * 4);
            xs[(kq * 4 + 0) * LDW + r] = v.x;
            xs[(kq * 4 + 1) * LDW + r] = v.y;
            xs[(kq * 4 + 2) * LDW + r] = v.z;
            xs[(kq * 4 + 3) * LDW + r] = v.w;
        }
#pragma unroll
        for (int j = 0; j < 4; ++j) {
            int l = tid + 256 * j;
            int kk = l >> 4, cq = l & 15;
            *(float4*)(ws + kk * LDW + cq * 4) = *(const float4*)(W0 + (size_t)(k0 + kk) * 64 + cq * 4);
        }
        __syncthreads();
#pragma unroll 4
        for (int k = 0; k < 64; ++k) {
            float4 a = *(const float4*)(xs + k * LDW + tr * 4);
            float4 w = *(const float4*)(ws + k * LDW + tc * 4);
            acc[0][0] = fmaf(a.x, w.x, acc[0][0]); acc[0][1] = fmaf(a.x, w.y, acc[0][1]);
            acc[0][2] = fmaf(a.x, w.z, acc[0][2]); acc[0][3] = fmaf(a.x, w.w, acc[0][3]);
            acc[1][0] = fmaf(a.y, w.x, acc[1][0]); acc[1][1] = fmaf(a.y, w.y, acc[1][1]);
            acc[1][2] = fmaf(a.y, w.z, acc[1][2]); acc[1][3] = fmaf(a.y, w.w, acc[1][3]);
            acc[2][0] = fmaf(a.z, w.x, acc[2][0]); acc[2][1] = fmaf(a.z, w.y, acc[2][1]);
            acc[2][2] = fmaf(a.z, w.z, acc[2][2]); acc[2][3] = fmaf(a.z, w.w, acc[2][3]);
            acc[3][0] = fmaf(a.w, w.x, acc[3][0]); acc[3][1] = fmaf(a.w, w.y, acc[3][1]);
            acc[3][2] = fmaf(a.w, w.z, acc[3][2]); acc[3][3] = fmaf(a.w, w.w, acc[3][3]);
        }
        __syncthreads();
    }
#pragma unroll
    for (int jj = 0; jj < 4; ++jj) {
        float b = b0[tc * 4 + jj];
        float4 v;
        v.x = fmaxf(acc[0][jj] + b, 0.f);
        v.y = fmaxf(acc[1][jj] + b, 0.f);
        v.z = fmaxf(acc[2][jj] + b, 0.f);
        v.w = fmaxf(acc[3][jj] + b, 0.f);
        *(float4*)(xs + (tc * 4 + jj) * LDW + tr * 4) = v;
    }
#pragma unroll
    for (int j = 0; j < 4; ++j) {
        int l = tid + 256 * j;
        int kk = l >> 4, cq = l & 15;
        *(float4*)(ws + kk * LDW + cq * 4) = *(const float4*)(W1 + (size_t)kk * 64 + cq * 4);
    }
    float acc2[4][4];
#pragma unroll
    for (int i = 0; i < 4; ++i)
#pragma unroll
        for (int j = 0; j < 4; ++j) acc2[i][j] = 0.f;
    __syncthreads();
#pragma unroll 4
    for (int k = 0; k < 64; ++k) {
        float4 a = *(const float4*)(xs + k * LDW + tr * 4);
        float4 w = *(const float4*)(ws + k * LDW + tc * 4);
        acc2[0][0] = fmaf(a.x, w.x, acc2[0][0]); acc2[0][1] = fmaf(a.x, w.y, acc2[0][1]);
        acc2[0][2] = fmaf(a.x, w.z, acc2[0][2]); acc2[0][3] = fmaf(a.x, w.w, acc2[0][3]);
        acc2[1][0] = fmaf(a.y, w.x, acc2[1][0]); acc2[1][1] = fmaf(a.y, w.y, acc2[1][1]);
        acc2[1][2] = fmaf(a.y, w.z, acc2[1][2]); acc2[1][3] = fmaf(a.y, w.w, acc2[1][3]);
        acc2[2][0] = fmaf(a.z, w.x, acc2[2][0]); acc2[2][1] = fmaf(a.z, w.y, acc2[2][1]);
        acc2[2][2] = fmaf(a.z, w.z, acc2[2][2]); acc2[2][3] = fmaf(a.z, w.w, acc2[2][3]);
        acc2[3][0] = fmaf(a.w, w.x, acc2[3][0]); acc2[3][1] = fmaf(a.w, w.y, acc2[3][1]);
        acc2[3][2] = fmaf(a.w, w.z, acc2[3][2]); acc2[3][3] = fmaf(a.w, w.w, acc2[3][3]);
    }
    float bv0 = b1[tc * 4 + 0], bv1 = b1[tc * 4 + 1], bv2 = b1[tc * 4 + 2], bv3 = b1[tc * 4 + 3];
#pragma unroll
    for (int i = 0; i < 4; ++i) {
        int gr = rbase + tr * 4 + i;
        if (gr < N) {
            float4 o = make_float4(acc2[i][0] + bv0, acc2[i][1] + bv1, acc2[i][2] + bv2, acc2[i][3] + bv3);
            *(float4*)(h + (size_t)gr * 64 + tc * 4) = o;
        }
    }
}

// ---- bf16 helpers ----
__device__ __forceinline__ float bf_lo(unsigned z) { return __uint_as_float(z << 16); }
__device__ __forceinline__ float bf_hi(unsigned z) { return __uint_as_float(z & 0xffff0000u); }
__device__ __forceinline__ unsigned bf_rne(float x) {
    unsigned u = __float_as_uint(x);
    return (u + 0x7fffu + ((u >> 16) & 1u)) >> 16;
}
__device__ __forceinline__ unsigned bf_pack(float x, float y) { return bf_rne(x) | (bf_rne(y) << 16); }

__global__ __launch_bounds__(256) void k_h2b(const float* __restrict__ h, unsigned* __restrict__ zb, int n2) {
    int i = blockIdx.x * 256 + threadIdx.x;
    if (i < n2) {
        float2 v = ((const float2*)h)[i];
        zb[i] = bf_pack(v.x, v.y);
    }
}

// ---- propagation: wave per dest, 2 edges x 32 lanes, bf16 z gather, unroll 8 ----
__global__ __launch_bounds__(256) void k_prop(const int2* __restrict__ srcw,
                                              const int* __restrict__ rowp, const int* __restrict__ cnt,
                                              const float* __restrict__ dinv,
                                              const unsigned* __restrict__ zin, const float* __restrict__ h,
                                              unsigned* __restrict__ zout_b, float* __restrict__ zout_f, int N) {
    int wid = (blockIdx.x << 2) | (threadIdx.x >> 6);
    int d = __builtin_amdgcn_readfirstlane(wid);  // wave-uniform -> scalar loads for per-dest data
    if (d >= N) return;
    int lane = threadIdx.x & 63;
    int half = lane >> 5, fi = lane & 31;  // lane handles features (2fi, 2fi+1) of edge parity `half`
    int beg = rowp[d], end = beg + cnt[d];
    float ax = 0.f, ay = 0.f;
    int e = beg + half;
    for (; e + 14 < end; e += 16) {  // 8 edges per parity in flight
        int2 p0 = srcw[e],      p1 = srcw[e + 2],  p2 = srcw[e + 4],  p3 = srcw[e + 6];
        int2 p4 = srcw[e + 8],  p5 = srcw[e + 10], p6 = srcw[e + 12], p7 = srcw[e + 14];
        unsigned z0 = zin[(size_t)p0.x * 32 + fi];
        unsigned z1 = zin[(size_t)p1.x * 32 + fi];
        unsigned z2 = zin[(size_t)p2.x * 32 + fi];
        unsigned z3 = zin[(size_t)p3.x * 32 + fi];
        unsigned z4 = zin[(size_t)p4.x * 32 + fi];
        unsigned z5 = zin[(size_t)p5.x * 32 + fi];
        unsigned z6 = zin[(size_t)p6.x * 32 + fi];
        unsigned z7 = zin[(size_t)p7.x * 32 + fi];
        float w0 = __int_as_float(p0.y), w1 = __int_as_float(p1.y);
        float w2 = __int_as_float(p2.y), w3 = __int_as_float(p3.y);
        float w4 = __int_as_float(p4.y), w5 = __int_as_float(p5.y);
        float w6 = __int_as_float(p6.y), w7 = __int_as_float(p7.y);
        ax = fmaf(w0, bf_lo(z0), ax); ay = fmaf(w0, bf_hi(z0), ay);
        ax = fmaf(w1, bf_lo(z1), ax); ay = fmaf(w1, bf_hi(z1), ay);
        ax = fmaf(w2, bf_lo(z2), ax); ay = fmaf(w2, bf_hi(z2), ay);
        ax = fmaf(w3, bf_lo(z3), ax); ay = fmaf(w3, bf_hi(z3), ay);
        ax = fmaf(w4, bf_lo(z4), ax); ay = fmaf(w4, bf_hi(z4), ay);
        ax = fmaf(w5, bf_lo(z5), ax); ay = fmaf(w5, bf_hi(z5), ay);
        ax = fmaf(w6, bf_lo(z6), ax); ay = fmaf(w6, bf_hi(z6), ay);
        ax = fmaf(w7, bf_lo(z7), ax); ay = fmaf(w7, bf_hi(z7), ay);
    }
    for (; e < end; e += 2) {
        int2 p = srcw[e];
        unsigned z = zin[(size_t)p.x * 32 + fi];
        float w = __int_as_float(p.y);
        ax = fmaf(w, bf_lo(z), ax); ay = fmaf(w, bf_hi(z), ay);
    }
    ax += __shfl_xor(ax, 32);
    ay += __shfl_xor(ay, 32);
    if (half == 0) {
        float di = dinv[d];
        unsigned zs = zin[(size_t)d * 32 + fi];  // analytic self-loop
        float s2 = di * di;
        float ox = 0.9f * (ax + s2 * bf_lo(zs));
        float oy = 0.9f * (ay + s2 * bf_hi(zs));
        float2 hv = ((const float2*)h)[(size_t)d * 32 + fi];
        ox = fmaf(0.1f, hv.x, ox);
        oy = fmaf(0.1f, hv.y, oy);
        if (zout_f) ((float2*)zout_f)[(size_t)d * 32 + fi] = make_float2(ox, oy);
        else zout_b[(size_t)d * 32 + fi] = bf_pack(ox, oy);
    }
}

extern "C" void kernel_launch(void* const* d_in, const int* in_sizes, int n_in,
                              void* d_out, int out_size, void* d_ws, size_t ws_size,
                              hipStream_t stream) {
    const float* x  = (const float*)d_in[0];
    const int*   ei = (const int*)d_in[1];
    const float* ew = (const float*)d_in[2];
    const float* W0 = (const float*)d_in[3];
    const float* b0 = (const float*)d_in[4];
    const float* W1 = (const float*)d_in[5];
    const float* b1 = (const float*)d_in[6];
    int N = in_sizes[0] / 512;
    int E = in_sizes[2];
    const int* row = ei;
    const int* col = ei + E;

    char* p = (char*)d_ws;
    auto alloc = [&](size_t bytes) -> char* {
        char* r = p;
        p += (bytes + 255) & ~(size_t)255;
        return r;
    };
    int NPg = (N + PAGE - 1) / PAGE;                         // 7 pages for N=100K
    size_t zbytes = (size_t)N * 32 * 4;                      // 12.8 MB per z buffer
    size_t slab_bytes = (size_t)NPg * BPP * PAGE * 4;        // 28.9 MB (BPP=64)
    float* h     = (float*)alloc((size_t)N * 64 * 4);        // 25.6 MB
    float* slabf = (float*)alloc(slab_bytes);                // dead after k_scat
    int2*  srcw  = (int2*)alloc((size_t)E * 8);              // 25.6 MB
    float* dinv  = (float*)alloc((size_t)N * 4);
    int* cnt     = (int*)alloc((size_t)N * 4);
    int* rowp    = (int*)alloc((size_t)N * 4);
    int* csum    = (int*)alloc(512 * 4);
    int* slabi   = (int*)slabf;  // sequential reuse: deg fold completes before k_cnt writes
    // zb0/zb1 overlay the slab region (slab is dead once k_scat finishes; stream order
    // guarantees k_h2b's writes happen after k_scat's last slab read).
    unsigned* zb0 = (unsigned*)slabf;
    unsigned* zb1 = (unsigned*)((char*)slabf + zbytes);

    int gN = (N + 255) / 256;
    int NC = (N + 1023) / 1024;
    int chunk = (((E + BPP - 1) / BPP) + 3) & ~3;
    int gridPg = NPg * BPP;

    k_deg<<<gridPg, 256, 0, stream>>>(row, ew, slabf, E, chunk);
    k_fold_deg<<<gN, 256, 0, stream>>>(slabf, dinv, N);
    k_cnt<<<gridPg, 256, 0, stream>>>(col, slabi, E, chunk);
    k_fold_cnt<<<gN, 256, 0, stream>>>(slabi, cnt, N);
    k_scanA<<<NC, 256, 0, stream>>>(cnt, csum, N);
    k_scanB<<<1, 256, 0, stream>>>(csum, NC);
    k_scanC<<<NC, 256, 0, stream>>>(cnt, csum, rowp, N);
    k_scat<<<gridPg, 256, 0, stream>>>(row, col, ew, dinv, rowp, slabi, srcw, E, chunk);
    k_mlp<<<(N + 63) / 64, 256, 0, stream>>>(x, W0, b0, W1, b1, h, N);
    k_h2b<<<(N * 32 + 255) / 256, 256, 0, stream>>>(h, zb0, N * 32);

    unsigned* zbufs[2] = { zb1, zb0 };  // iter it writes zbufs[it&1] (bf16) except final
    const unsigned* zi = zb0;
    int gP = (N + 3) / 4;
    for (int it = 0; it < 10; ++it) {
        if (it < 9) {
            unsigned* zo = zbufs[it & 1];
            k_prop<<<gP, 256, 0, stream>>>(srcw, rowp, cnt, dinv, zi, h, zo, nullptr, N);
            zi = zo;
        } else {
            k_prop<<<gP, 256, 0, stream>>>(srcw, rowp, cnt, dinv, zi, h, nullptr, (float*)d_out, N);
        }
    }
}